// Round 2
// baseline (2221.212 us; speedup 1.0000x reference)
//
#include <hip/hip_runtime.h>

// Problem constants
#define CDIM   192
#define NHEADS 6
#define KDIM   32
#define NTOK   49          // tokens per window (7x7)
#define NPIX   3136        // 56*56
#define NB     32
#define NWIN   2048        // 32 * 8 * 8
#define CHUNKW 512         // windows per chunk
#define NCHUNK 4
#define CHUNKM (CHUNKW*NTOK)   // 25088
#define QKVN   576
#define HIDDEN 768
#define LN_EPS 1e-5f
#define BN_EPS 1e-5f
#define WSTR   28224       // 3*6*49*32 floats per window in qkv scratch
#define NTOKALL 100352     // 32*3136

// ---------------------------------------------------------------- k0: LN1 stats
__global__ void k0_stats(const float* __restrict__ x, float* __restrict__ mv) {
    int t    = blockIdx.x * 4 + (threadIdx.x >> 6);
    int lane = threadIdx.x & 63;
    const float* row = x + (size_t)t * CDIM;
    float e0 = row[lane], e1 = row[lane + 64], e2 = row[lane + 128];
    float s = e0 + e1 + e2;
    for (int o = 32; o; o >>= 1) s += __shfl_xor(s, o);
    float m = s * (1.0f / 192.0f);
    float d0 = e0 - m, d1 = e1 - m, d2 = e2 - m;
    float v = d0*d0 + d1*d1 + d2*d2;
    for (int o = 32; o; o >>= 1) v += __shfl_xor(v, o);
    if (lane == 0) {
        mv[t] = m;
        mv[NTOKALL + t] = 1.0f / sqrtf(v * (1.0f / 192.0f) + LN_EPS);
    }
}

// ------------------------------------------------------- k1: LN-fused QKV GEMM
// C[m][n] = LN(x)[m][:] @ qkv_w[:][n] + qkv_b[n]
// scatter to ws layout [wrel][part][head][tok][d]; n -> head=n/96, part, d
__global__ __launch_bounds__(256) void k1_qkv(
    const float* __restrict__ x,  const float* __restrict__ mv,
    const float* __restrict__ g1, const float* __restrict__ b1,
    const float* __restrict__ wq, const float* __restrict__ qb,
    float* __restrict__ qkv, int wbase)
{
    __shared__ float As[32 * 68];
    __shared__ float Bs[32 * 68];
    const int tid = threadIdx.x;
    const int m0 = blockIdx.x * 64;
    const int n0 = blockIdx.y * 64;
    const int ty = tid >> 4, tx = tid & 15;

    const int ar0 = tid >> 3;   // 0..31, row within tile (p=0)
    const int aq  = tid & 7;    // k-quad
    size_t axbase[2]; float amean[2], arstd[2];
#pragma unroll
    for (int p = 0; p < 2; ++p) {
        int m  = m0 + ar0 + p * 32;
        int gt = wbase * NTOK + m;
        int w = gt / 49, tok = gt - w * 49;
        int b = w >> 6, wrem = w & 63;
        int wi = wrem >> 3, wj = wrem & 7;
        int r = tok / 7, c = tok - r * 7;
        int xrow = b * NPIX + (wi * 7 + r) * 56 + wj * 7 + c;
        axbase[p] = (size_t)xrow * CDIM;
        amean[p] = mv[xrow];                 // FIX: mv is x-row-major indexed
        arstd[p] = mv[NTOKALL + xrow];       // FIX: was mv[gt] (window-major)
    }
    const int br0 = tid >> 4;   // 0..15
    const int bq  = tid & 15;

    float acc[4][4] = {};
    for (int k0 = 0; k0 < CDIM; k0 += 32) {
        float4 gv = *(const float4*)&g1[k0 + aq * 4];
        float4 bv = *(const float4*)&b1[k0 + aq * 4];
#pragma unroll
        for (int p = 0; p < 2; ++p) {
            float4 xv = *(const float4*)&x[axbase[p] + k0 + aq * 4];
            float mm = amean[p], rs = arstd[p];
            int a = ar0 + p * 32;
            As[(aq * 4 + 0) * 68 + a] = (xv.x - mm) * rs * gv.x + bv.x;
            As[(aq * 4 + 1) * 68 + a] = (xv.y - mm) * rs * gv.y + bv.y;
            As[(aq * 4 + 2) * 68 + a] = (xv.z - mm) * rs * gv.z + bv.z;
            As[(aq * 4 + 3) * 68 + a] = (xv.w - mm) * rs * gv.w + bv.w;
        }
#pragma unroll
        for (int p = 0; p < 2; ++p) {
            int brr = br0 + p * 16;
            *(float4*)&Bs[brr * 68 + bq * 4] =
                *(const float4*)&wq[(size_t)(k0 + brr) * QKVN + n0 + bq * 4];
        }
        __syncthreads();
#pragma unroll
        for (int k = 0; k < 32; ++k) {
            float4 a4 = *(const float4*)&As[k * 68 + ty * 4];
            float4 b4 = *(const float4*)&Bs[k * 68 + tx * 4];
            float av[4] = {a4.x, a4.y, a4.z, a4.w};
            float bw[4] = {b4.x, b4.y, b4.z, b4.w};
#pragma unroll
            for (int i = 0; i < 4; ++i)
#pragma unroll
                for (int j = 0; j < 4; ++j) acc[i][j] += av[i] * bw[j];
        }
        __syncthreads();
    }
#pragma unroll
    for (int i = 0; i < 4; ++i) {
        int m = m0 + ty * 4 + i;
        int wrel = m / 49, tok = m - wrel * 49;
        size_t obase = (size_t)wrel * WSTR + tok * 32;
#pragma unroll
        for (int j = 0; j < 4; ++j) {
            int n = n0 + tx * 4 + j;
            int h = n / 96, rem = n - h * 96;
            int part = rem >> 5, d = rem & 31;
            qkv[obase + (size_t)(part * 6 + h) * 1568 + d] = acc[i][j] + qb[n];
        }
    }
}

// ----------------------------------------------- k2: windowed attention (head pair)
__global__ __launch_bounds__(128) void k2_attn(
    float* __restrict__ qkv, const float* __restrict__ abias)
{
    __shared__ float kv[6272];   // [kv part(2)][h(2)][tok 49][d 32]
    const int wrel = blockIdx.x / 3;
    const int pair = blockIdx.x - wrel * 3;
    const int h0 = pair * 2;
    float* base = qkv + (size_t)wrel * WSTR;
    for (int idx = threadIdx.x; idx < 1568; idx += 128) {
        int part = idx / 784;
        int rem  = idx - part * 784;
        int h    = rem / 392;
        int rem2 = rem - h * 392;          // tok*8 + dq
        *(float4*)&kv[idx * 4] =
            *(const float4*)&base[(size_t)((part + 1) * 6 + h0 + h) * 1568 + rem2 * 4];
    }
    __syncthreads();
    const int item = threadIdx.x;
    if (item >= 98) return;
    const int h = item / 49;
    const int row = item - h * 49;
    const int hg = h0 + h;
    float* qptr = base + (size_t)hg * 1568 + row * 32;
    float4 q4[8];
#pragma unroll
    for (int dq = 0; dq < 8; ++dq) q4[dq] = *(const float4*)&qptr[dq * 4];
    const int rr = row / 7, rc = row - rr * 7;
    const float scale = 0.17677669529663687f;   // 32^-0.5
    const float* kbase = &kv[(h * 49) * 32];
    const float* vbase = &kv[(98 + h * 49) * 32];
    float s[49];
    for (int j = 0; j < 49; ++j) {
        const float* kr = kbase + j * 32;
        float4 a = {0, 0, 0, 0};
#pragma unroll
        for (int dq = 0; dq < 8; ++dq) {
            float4 k4 = *(const float4*)&kr[dq * 4];
            a.x += q4[dq].x * k4.x; a.y += q4[dq].y * k4.y;
            a.z += q4[dq].z * k4.z; a.w += q4[dq].w * k4.w;
        }
        int jr = j / 7, jc = j - jr * 7;
        int dy = rr > jr ? rr - jr : jr - rr;
        int dx = rc > jc ? rc - jc : jc - rc;
        s[j] = (a.x + a.y + a.z + a.w) * scale + abias[hg * 49 + dy * 7 + dx];
    }
    float mx = s[0];
    for (int j = 1; j < 49; ++j) mx = fmaxf(mx, s[j]);
    float sum = 0.0f;
    for (int j = 0; j < 49; ++j) { s[j] = expf(s[j] - mx); sum += s[j]; }
    float rinv = 1.0f / sum;
    float4 o[8] = {};
    for (int j = 0; j < 49; ++j) {
        float p = s[j];
        const float* vr = vbase + j * 32;
#pragma unroll
        for (int dq = 0; dq < 8; ++dq) {
            float4 v4 = *(const float4*)&vr[dq * 4];
            o[dq].x += p * v4.x; o[dq].y += p * v4.y;
            o[dq].z += p * v4.z; o[dq].w += p * v4.w;
        }
    }
#pragma unroll
    for (int dq = 0; dq < 8; ++dq) {
        float4 ov = {o[dq].x * rinv, o[dq].y * rinv, o[dq].z * rinv, o[dq].w * rinv};
        *(float4*)&qptr[dq * 4] = ov;     // overwrite q slot (own row only)
    }
}

// ---------------------------------- k3: proj GEMM + bias + residual + window reverse
__global__ __launch_bounds__(256) void k3_proj(
    const float* __restrict__ qkv, const float* __restrict__ x,
    const float* __restrict__ wp,  const float* __restrict__ pb,
    float* __restrict__ x1, int wbase)
{
    __shared__ float As[32 * 68];
    __shared__ float Bs[32 * 68];
    const int tid = threadIdx.x;
    const int m0 = blockIdx.x * 64;
    const int n0 = blockIdx.y * 64;
    const int ty = tid >> 4, tx = tid & 15;
    const int ar0 = tid >> 3, aq = tid & 7;
    size_t abase[2];
#pragma unroll
    for (int p = 0; p < 2; ++p) {
        int m = m0 + ar0 + p * 32;
        int wrel = m / 49, tok = m - wrel * 49;
        abase[p] = (size_t)wrel * WSTR + tok * 32;
    }
    const int br0 = tid >> 4, bq = tid & 15;
    float acc[4][4] = {};
    for (int k0 = 0; k0 < CDIM; k0 += 32) {
        int hh = k0 >> 5;
#pragma unroll
        for (int p = 0; p < 2; ++p) {
            float4 av = *(const float4*)&qkv[abase[p] + (size_t)hh * 1568 + aq * 4];
            int a = ar0 + p * 32;
            As[(aq * 4 + 0) * 68 + a] = av.x;
            As[(aq * 4 + 1) * 68 + a] = av.y;
            As[(aq * 4 + 2) * 68 + a] = av.z;
            As[(aq * 4 + 3) * 68 + a] = av.w;
        }
#pragma unroll
        for (int p = 0; p < 2; ++p) {
            int brr = br0 + p * 16;
            *(float4*)&Bs[brr * 68 + bq * 4] =
                *(const float4*)&wp[(size_t)(k0 + brr) * CDIM + n0 + bq * 4];
        }
        __syncthreads();
#pragma unroll
        for (int k = 0; k < 32; ++k) {
            float4 a4 = *(const float4*)&As[k * 68 + ty * 4];
            float4 b4 = *(const float4*)&Bs[k * 68 + tx * 4];
            float av[4] = {a4.x, a4.y, a4.z, a4.w};
            float bw[4] = {b4.x, b4.y, b4.z, b4.w};
#pragma unroll
            for (int i = 0; i < 4; ++i)
#pragma unroll
                for (int j = 0; j < 4; ++j) acc[i][j] += av[i] * bw[j];
        }
        __syncthreads();
    }
    float4 pbv = *(const float4*)&pb[n0 + tx * 4];
#pragma unroll
    for (int i = 0; i < 4; ++i) {
        int m = m0 + ty * 4 + i;
        int wrel = m / 49, tok = m - wrel * 49;
        int w = wbase + wrel;
        int b = w >> 6, wrem = w & 63;
        int wi = wrem >> 3, wj = wrem & 7;
        int r = tok / 7, c = tok - r * 7;
        size_t xoff = ((size_t)(b * NPIX + (wi * 7 + r) * 56 + wj * 7 + c)) * CDIM
                      + n0 + tx * 4;
        float4 rv = *(const float4*)&x[xoff];
        float4 ov = {acc[i][0] + pbv.x + rv.x, acc[i][1] + pbv.y + rv.y,
                     acc[i][2] + pbv.z + rv.z, acc[i][3] + pbv.w + rv.w};
        *(float4*)&x1[xoff] = ov;
    }
}

// ------------------------------------------------------- k4: depthwise conv3x3 + BN
__global__ void k4_conv(const float* __restrict__ x1, const float* __restrict__ cw,
                        const float* __restrict__ bg, const float* __restrict__ bb,
                        const float* __restrict__ bm, const float* __restrict__ bv,
                        float* __restrict__ x2)
{
    int idx = blockIdx.x * 256 + threadIdx.x;     // ((b*3136+l)*48 + cq)
    int cq  = idx % 48;
    int rem = idx / 48;
    int xx  = rem % 56; rem /= 56;
    int yy  = rem % 56;
    int b   = rem / 56;
    int c0  = cq * 4;
    const float* xb = x1 + (size_t)b * NPIX * CDIM;
    float4 acc = {0, 0, 0, 0};
#pragma unroll
    for (int dy = -1; dy <= 1; ++dy) {
        int y2 = yy + dy;
        if ((unsigned)y2 >= 56u) continue;
#pragma unroll
        for (int dx = -1; dx <= 1; ++dx) {
            int x2c = xx + dx;
            if ((unsigned)x2c >= 56u) continue;
            float4 v = *(const float4*)&xb[(size_t)(y2 * 56 + x2c) * CDIM + c0];
            int tap = (dy + 1) * 3 + (dx + 1);
            acc.x += v.x * cw[(c0 + 0) * 9 + tap];
            acc.y += v.y * cw[(c0 + 1) * 9 + tap];
            acc.z += v.z * cw[(c0 + 2) * 9 + tap];
            acc.w += v.w * cw[(c0 + 3) * 9 + tap];
        }
    }
    float4 o;
    o.x = (acc.x - bm[c0 + 0]) * (bg[c0 + 0] / sqrtf(bv[c0 + 0] + BN_EPS)) + bb[c0 + 0];
    o.y = (acc.y - bm[c0 + 1]) * (bg[c0 + 1] / sqrtf(bv[c0 + 1] + BN_EPS)) + bb[c0 + 1];
    o.z = (acc.z - bm[c0 + 2]) * (bg[c0 + 2] / sqrtf(bv[c0 + 2] + BN_EPS)) + bb[c0 + 2];
    o.w = (acc.w - bm[c0 + 3]) * (bg[c0 + 3] / sqrtf(bv[c0 + 3] + BN_EPS)) + bb[c0 + 3];
    *(float4*)&x2[(size_t)idx * 4] = o;
}

// ----------------------------------------- k5: LN2 + FC1 + GELU + FC2 + residual
__global__ __launch_bounds__(256) void k5_mlp(
    const float* __restrict__ x2, const float* __restrict__ g2, const float* __restrict__ b2,
    const float* __restrict__ w1, const float* __restrict__ fb1,
    const float* __restrict__ w2, const float* __restrict__ fb2,
    float* __restrict__ out)
{
    __shared__ float ln[32][196];
    __shared__ float hbuf[32][132];
    const int t0 = blockIdx.x * 32;
    const int tid = threadIdx.x, wave = tid >> 6, lane = tid & 63;
    const float g20 = g2[lane], g21 = g2[lane + 64], g22 = g2[lane + 128];
    const float b20 = b2[lane], b21 = b2[lane + 64], b22 = b2[lane + 128];
    for (int tt = wave; tt < 32; tt += 4) {
        const float* row = x2 + (size_t)(t0 + tt) * CDIM;
        float e0 = row[lane], e1 = row[lane + 64], e2 = row[lane + 128];
        float s = e0 + e1 + e2;
        for (int o = 32; o; o >>= 1) s += __shfl_xor(s, o);
        float m = s * (1.0f / 192.0f);
        float d0 = e0 - m, d1 = e1 - m, d2 = e2 - m;
        float v = d0*d0 + d1*d1 + d2*d2;
        for (int o = 32; o; o >>= 1) v += __shfl_xor(v, o);
        float rs = 1.0f / sqrtf(v * (1.0f / 192.0f) + LN_EPS);
        ln[tt][lane]       = d0 * rs * g20 + b20;
        ln[tt][lane + 64]  = d1 * rs * g21 + b21;
        ln[tt][lane + 128] = d2 * rs * g22 + b22;
    }
    __syncthreads();

    float acc2[8][3] = {};
    for (int ch = 0; ch < 6; ++ch) {
        // FC1: rows wave*8..+7, cols {ch*128 + lane*2, +1}
        float a1[8][2] = {};
        for (int k4 = 0; k4 < CDIM; k4 += 4) {
            float2 bw[4];
#pragma unroll
            for (int kk = 0; kk < 4; ++kk)
                bw[kk] = *(const float2*)&w1[(size_t)(k4 + kk) * HIDDEN + ch * 128 + lane * 2];
#pragma unroll
            for (int r = 0; r < 8; ++r) {
                float4 a4 = *(const float4*)&ln[wave * 8 + r][k4];
                a1[r][0] += a4.x * bw[0].x + a4.y * bw[1].x + a4.z * bw[2].x + a4.w * bw[3].x;
                a1[r][1] += a4.x * bw[0].y + a4.y * bw[1].y + a4.z * bw[2].y + a4.w * bw[3].y;
            }
        }
        __syncthreads();   // previous chunk's hbuf readers done
#pragma unroll
        for (int r = 0; r < 8; ++r) {
            float h0 = a1[r][0] + fb1[ch * 128 + lane * 2];
            float h1 = a1[r][1] + fb1[ch * 128 + lane * 2 + 1];
            h0 = h0 * 0.5f * (1.0f + erff(h0 * 0.70710678118654752f));
            h1 = h1 * 0.5f * (1.0f + erff(h1 * 0.70710678118654752f));
            float2 hv = {h0, h1};
            *(float2*)&hbuf[wave * 8 + r][lane * 2] = hv;
        }
        __syncthreads();
        // FC2 partial: rows wave*8..+7, cols {lane + 64c}
        for (int k4 = 0; k4 < 128; k4 += 4) {
            float bw[4][3];
#pragma unroll
            for (int kk = 0; kk < 4; ++kk)
#pragma unroll
                for (int c = 0; c < 3; ++c)
                    bw[kk][c] = w2[(size_t)(ch * 128 + k4 + kk) * CDIM + c * 64 + lane];
#pragma unroll
            for (int r = 0; r < 8; ++r) {
                float4 a4 = *(const float4*)&hbuf[wave * 8 + r][k4];
#pragma unroll
                for (int c = 0; c < 3; ++c)
                    acc2[r][c] += a4.x * bw[0][c] + a4.y * bw[1][c]
                                + a4.z * bw[2][c] + a4.w * bw[3][c];
            }
        }
    }
#pragma unroll
    for (int r = 0; r < 8; ++r) {
        int t = t0 + wave * 8 + r;
#pragma unroll
        for (int c = 0; c < 3; ++c) {
            int col = c * 64 + lane;
            out[(size_t)t * CDIM + col] = acc2[r][c] + fb2[col] + x2[(size_t)t * CDIM + col];
        }
    }
}

// ------------------------------------------------------------------- launcher
extern "C" void kernel_launch(void* const* d_in, const int* in_sizes, int n_in,
                              void* d_out, int out_size, void* d_ws, size_t ws_size,
                              hipStream_t stream) {
    const float* x     = (const float*)d_in[0];
    const float* g1    = (const float*)d_in[1];
    const float* b1    = (const float*)d_in[2];
    const float* qkvw  = (const float*)d_in[3];
    const float* qkvb  = (const float*)d_in[4];
    const float* abias = (const float*)d_in[5];
    const float* projw = (const float*)d_in[6];
    const float* projb = (const float*)d_in[7];
    const float* convw = (const float*)d_in[8];
    const float* bng   = (const float*)d_in[9];
    const float* bnb   = (const float*)d_in[10];
    const float* bnm   = (const float*)d_in[11];
    const float* bnv   = (const float*)d_in[12];
    const float* g2    = (const float*)d_in[13];
    const float* b2    = (const float*)d_in[14];
    const float* fc1w  = (const float*)d_in[15];
    const float* fc1b  = (const float*)d_in[16];
    const float* fc2w  = (const float*)d_in[17];
    const float* fc2b  = (const float*)d_in[18];
    float* out = (float*)d_out;

    // ws layout (floats): [0, 19267584) = qkv chunk scratch (14.45M) / later x2 (19.27M)
    //                     [19267584, 19468288) = LN1 mean/rstd.  Needs 77,873,152 B.
    float* wsf   = (float*)d_ws;
    float* qkvws = wsf;
    float* x2b   = wsf;
    float* mv    = wsf + 19267584;

    k0_stats<<<NTOKALL / 4, 256, 0, stream>>>(x, mv);
    for (int chunk = 0; chunk < NCHUNK; ++chunk) {
        int wbase = chunk * CHUNKW;
        k1_qkv<<<dim3(CHUNKM / 64, QKVN / 64), 256, 0, stream>>>(
            x, mv, g1, b1, qkvw, qkvb, qkvws, wbase);
        k2_attn<<<CHUNKW * 3, 128, 0, stream>>>(qkvws, abias);
        k3_proj<<<dim3(CHUNKM / 64, CDIM / 64), 256, 0, stream>>>(
            qkvws, x, projw, projb, out, wbase);
    }
    k4_conv<<<(NB * NPIX * 48) / 256, 256, 0, stream>>>(out, convw, bng, bnb, bnm, bnv, x2b);
    k5_mlp<<<NTOKALL / 32, 256, 0, stream>>>(x2b, g2, b2, fc1w, fc1b, fc2w, fc2b, out);
}

// Round 3
// 1276.061 us; speedup vs baseline: 1.7407x; 1.7407x over previous
//
#include <hip/hip_runtime.h>

// Problem constants
#define CDIM   192
#define NHEADS 6
#define KDIM   32
#define NTOK   49          // tokens per window (7x7)
#define NPIX   3136        // 56*56
#define NB     32
#define NWIN   2048        // 32 * 8 * 8
#define CHUNKW 512         // windows per chunk
#define NCHUNK 4
#define CHUNKM (CHUNKW*NTOK)   // 25088
#define QKVN   576
#define HIDDEN 768
#define LN_EPS 1e-5f
#define BN_EPS 1e-5f
#define WSTR   28224       // 3*6*49*32 floats per window in qkv scratch
#define NTOKALL 100352     // 32*3136

typedef __attribute__((ext_vector_type(8))) short bf16x8;   // 8 bf16 = 4 VGPRs
typedef __attribute__((ext_vector_type(4))) float f32x4;

__device__ __forceinline__ unsigned short f2bf(float f) {
    unsigned u = __float_as_uint(f);
    return (unsigned short)((u + 0x7FFFu + ((u >> 16) & 1u)) >> 16);   // RNE
}

// ------------------------------------------- weight swizzle: fp32 KxN -> bf16 frags
// frag layout: subtile id = (n0/16)*(K/32) + (k0/32); lane L holds
// W[k0 + (L>>4)*8 + j][n0 + (L&15)], j=0..7, stored as 16B per lane.
__global__ void kw_swz(const float* __restrict__ W, unsigned short* __restrict__ o,
                       int K, int N) {
    int t = blockIdx.x * 256 + threadIdx.x;
    int lane = t & 63, sub = t >> 6;
    int ksub = K >> 5;
    int total = (N >> 4) * ksub;
    if (sub >= total) return;
    int nfr = sub / ksub, kk = sub - nfr * ksub;
    int n = nfr * 16 + (lane & 15);
    int kb = kk * 32 + (lane >> 4) * 8;
    unsigned p0 = (unsigned)f2bf(W[(size_t)(kb + 0) * N + n]) |
                  ((unsigned)f2bf(W[(size_t)(kb + 1) * N + n]) << 16);
    unsigned p1 = (unsigned)f2bf(W[(size_t)(kb + 2) * N + n]) |
                  ((unsigned)f2bf(W[(size_t)(kb + 3) * N + n]) << 16);
    unsigned p2 = (unsigned)f2bf(W[(size_t)(kb + 4) * N + n]) |
                  ((unsigned)f2bf(W[(size_t)(kb + 5) * N + n]) << 16);
    unsigned p3 = (unsigned)f2bf(W[(size_t)(kb + 6) * N + n]) |
                  ((unsigned)f2bf(W[(size_t)(kb + 7) * N + n]) << 16);
    uint4 v = {p0, p1, p2, p3};
    *(uint4*)(o + (size_t)(sub * 64 + lane) * 8) = v;
}

// ---------------------------------------------------------------- k0: LN stats
__global__ void k0_stats(const float* __restrict__ x, float* __restrict__ mv) {
    int t    = blockIdx.x * 4 + (threadIdx.x >> 6);
    int lane = threadIdx.x & 63;
    const float* row = x + (size_t)t * CDIM;
    float e0 = row[lane], e1 = row[lane + 64], e2 = row[lane + 128];
    float s = e0 + e1 + e2;
    for (int o = 32; o; o >>= 1) s += __shfl_xor(s, o);
    float m = s * (1.0f / 192.0f);
    float d0 = e0 - m, d1 = e1 - m, d2 = e2 - m;
    float v = d0*d0 + d1*d1 + d2*d2;
    for (int o = 32; o; o >>= 1) v += __shfl_xor(v, o);
    if (lane == 0) {
        mv[t] = m;
        mv[NTOKALL + t] = 1.0f / sqrtf(v * (1.0f / 192.0f) + LN_EPS);
    }
}

// ------------------------------------------------- k1: LN1 + QKV GEMM (MFMA bf16)
// M-tile 64 (wave w = m-frag w), N-tile 192 (12 n-frags), K=192 (6 k-steps)
__global__ __launch_bounds__(256) void k1_qkv_mfma(
    const float* __restrict__ x,  const float* __restrict__ mv,
    const float* __restrict__ g1, const float* __restrict__ b1,
    const unsigned short* __restrict__ wsw, const float* __restrict__ qb,
    float* __restrict__ qkv, int wbase)
{
    const int tid = threadIdx.x;
    const int w = tid >> 6, L = tid & 63, quad = L >> 4, l15 = L & 15;
    const int m0 = blockIdx.x * 64;
    const int Nt = blockIdx.y;                 // 0..2
    // ---- A fragments: LN1(x) on the fly, one row per lane
    int mA = m0 + w * 16 + l15;
    int gt = wbase * NTOK + mA;
    int wg = gt / 49, tok = gt - wg * 49;
    int bb = wg >> 6, wrem = wg & 63;
    int rr = tok / 7, cc = tok - rr * 7;
    int xrow = bb * NPIX + ((wrem >> 3) * 7 + rr) * 56 + (wrem & 7) * 7 + cc;
    float mean = mv[xrow], rstd = mv[NTOKALL + xrow];
    const float* xr = x + (size_t)xrow * CDIM;
    bf16x8 a[6];
#pragma unroll
    for (int kk = 0; kk < 6; ++kk) {
        int c0 = kk * 32 + quad * 8;
        float4 xv0 = *(const float4*)&xr[c0], xv1 = *(const float4*)&xr[c0 + 4];
        float4 gv0 = *(const float4*)&g1[c0], gv1 = *(const float4*)&g1[c0 + 4];
        float4 bv0 = *(const float4*)&b1[c0], bv1 = *(const float4*)&b1[c0 + 4];
        bf16x8 av;
        av[0] = (short)f2bf((xv0.x - mean) * rstd * gv0.x + bv0.x);
        av[1] = (short)f2bf((xv0.y - mean) * rstd * gv0.y + bv0.y);
        av[2] = (short)f2bf((xv0.z - mean) * rstd * gv0.z + bv0.z);
        av[3] = (short)f2bf((xv0.w - mean) * rstd * gv0.w + bv0.w);
        av[4] = (short)f2bf((xv1.x - mean) * rstd * gv1.x + bv1.x);
        av[5] = (short)f2bf((xv1.y - mean) * rstd * gv1.y + bv1.y);
        av[6] = (short)f2bf((xv1.z - mean) * rstd * gv1.z + bv1.z);
        av[7] = (short)f2bf((xv1.w - mean) * rstd * gv1.w + bv1.w);
        a[kk] = av;
    }
    f32x4 acc[12];
#pragma unroll
    for (int nf = 0; nf < 12; ++nf) acc[nf] = (f32x4){0.f, 0.f, 0.f, 0.f};
    const bf16x8* B = (const bf16x8*)wsw;
#pragma unroll
    for (int kk = 0; kk < 6; ++kk) {
#pragma unroll
        for (int nf = 0; nf < 12; ++nf) {
            bf16x8 bfr = B[(size_t)((Nt * 12 + nf) * 6 + kk) * 64 + L];
            acc[nf] = __builtin_amdgcn_mfma_f32_16x16x32_bf16(a[kk], bfr, acc[nf], 0, 0, 0);
        }
    }
    // ---- epilogue: + qkv_b, scatter to [wrel][part][head][tok][d]
    float qbv[12];
#pragma unroll
    for (int nf = 0; nf < 12; ++nf) qbv[nf] = qb[Nt * 192 + nf * 16 + l15];
#pragma unroll
    for (int i = 0; i < 4; ++i) {
        int mrow = m0 + w * 16 + quad * 4 + i;
        int wrel = mrow / 49, tokr = mrow - wrel * 49;
        float* obase = qkv + (size_t)wrel * WSTR + tokr * 32;
#pragma unroll
        for (int nf = 0; nf < 12; ++nf) {
            int n = Nt * 192 + nf * 16 + l15;
            int h = n / 96, rem = n - h * 96;
            int part = rem >> 5, d = rem & 31;
            obase[(size_t)(part * 6 + h) * 1568 + d] = acc[nf][i] + qbv[nf];
        }
    }
}

// ----------------------------------------------- k2: windowed attention (head pair)
__global__ __launch_bounds__(128) void k2_attn(
    float* __restrict__ qkv, const float* __restrict__ abias)
{
    __shared__ float kv[6272];   // [kv part(2)][h(2)][tok 49][d 32]
    const int wrel = blockIdx.x / 3;
    const int pair = blockIdx.x - wrel * 3;
    const int h0 = pair * 2;
    float* base = qkv + (size_t)wrel * WSTR;
    for (int idx = threadIdx.x; idx < 1568; idx += 128) {
        int part = idx / 784;
        int rem  = idx - part * 784;
        int h    = rem / 392;
        int rem2 = rem - h * 392;          // tok*8 + dq
        *(float4*)&kv[idx * 4] =
            *(const float4*)&base[(size_t)((part + 1) * 6 + h0 + h) * 1568 + rem2 * 4];
    }
    __syncthreads();
    const int item = threadIdx.x;
    if (item >= 98) return;
    const int h = item / 49;
    const int row = item - h * 49;
    const int hg = h0 + h;
    float* qptr = base + (size_t)hg * 1568 + row * 32;
    float4 q4[8];
#pragma unroll
    for (int dq = 0; dq < 8; ++dq) q4[dq] = *(const float4*)&qptr[dq * 4];
    const int rr = row / 7, rc = row - rr * 7;
    const float scale = 0.17677669529663687f;   // 32^-0.5
    const float* kbase = &kv[(h * 49) * 32];
    const float* vbase = &kv[(98 + h * 49) * 32];
    float s[49];
    for (int j = 0; j < 49; ++j) {
        const float* kr = kbase + j * 32;
        float4 a = {0, 0, 0, 0};
#pragma unroll
        for (int dq = 0; dq < 8; ++dq) {
            float4 k4 = *(const float4*)&kr[dq * 4];
            a.x += q4[dq].x * k4.x; a.y += q4[dq].y * k4.y;
            a.z += q4[dq].z * k4.z; a.w += q4[dq].w * k4.w;
        }
        int jr = j / 7, jc = j - jr * 7;
        int dy = rr > jr ? rr - jr : jr - rr;
        int dx = rc > jc ? rc - jc : jc - rc;
        s[j] = (a.x + a.y + a.z + a.w) * scale + abias[hg * 49 + dy * 7 + dx];
    }
    float mx = s[0];
    for (int j = 1; j < 49; ++j) mx = fmaxf(mx, s[j]);
    float sum = 0.0f;
    for (int j = 0; j < 49; ++j) { s[j] = expf(s[j] - mx); sum += s[j]; }
    float rinv = 1.0f / sum;
    float4 o[8] = {};
    for (int j = 0; j < 49; ++j) {
        float p = s[j];
        const float* vr = vbase + j * 32;
#pragma unroll
        for (int dq = 0; dq < 8; ++dq) {
            float4 v4 = *(const float4*)&vr[dq * 4];
            o[dq].x += p * v4.x; o[dq].y += p * v4.y;
            o[dq].z += p * v4.z; o[dq].w += p * v4.w;
        }
    }
#pragma unroll
    for (int dq = 0; dq < 8; ++dq) {
        float4 ov = {o[dq].x * rinv, o[dq].y * rinv, o[dq].z * rinv, o[dq].w * rinv};
        *(float4*)&qptr[dq * 4] = ov;     // overwrite q slot (own row only)
    }
}

// --------------------------- k3: proj GEMM (MFMA) + bias + residual + window reverse
__global__ __launch_bounds__(256) void k3_proj_mfma(
    const float* __restrict__ qkv, const float* __restrict__ x,
    const unsigned short* __restrict__ wsw, const float* __restrict__ pb,
    float* __restrict__ x1, int wbase)
{
    const int tid = threadIdx.x;
    const int w = tid >> 6, L = tid & 63, quad = L >> 4, l15 = L & 15;
    const int m0 = blockIdx.x * 64;
    // ---- A fragments from attention output (q slots), layout [head][tok][32]
    int mA = m0 + w * 16 + l15;
    int wrelA = mA / 49, tokA = mA - wrelA * 49;
    const float* ar = qkv + (size_t)wrelA * WSTR + tokA * 32;
    bf16x8 a[6];
#pragma unroll
    for (int kk = 0; kk < 6; ++kk) {      // head = kk (c0 = kk*32)
        const float* p = ar + (size_t)kk * 1568 + quad * 8;
        float4 v0 = *(const float4*)&p[0], v1 = *(const float4*)&p[4];
        bf16x8 av;
        av[0] = (short)f2bf(v0.x); av[1] = (short)f2bf(v0.y);
        av[2] = (short)f2bf(v0.z); av[3] = (short)f2bf(v0.w);
        av[4] = (short)f2bf(v1.x); av[5] = (short)f2bf(v1.y);
        av[6] = (short)f2bf(v1.z); av[7] = (short)f2bf(v1.w);
        a[kk] = av;
    }
    f32x4 acc[12];
#pragma unroll
    for (int nf = 0; nf < 12; ++nf) acc[nf] = (f32x4){0.f, 0.f, 0.f, 0.f};
    const bf16x8* B = (const bf16x8*)wsw;
#pragma unroll
    for (int kk = 0; kk < 6; ++kk) {
#pragma unroll
        for (int nf = 0; nf < 12; ++nf) {
            bf16x8 bfr = B[(size_t)(nf * 6 + kk) * 64 + L];
            acc[nf] = __builtin_amdgcn_mfma_f32_16x16x32_bf16(a[kk], bfr, acc[nf], 0, 0, 0);
        }
    }
    float pbv[12];
#pragma unroll
    for (int nf = 0; nf < 12; ++nf) pbv[nf] = pb[nf * 16 + l15];
#pragma unroll
    for (int i = 0; i < 4; ++i) {
        int mrow = m0 + w * 16 + quad * 4 + i;
        int wrel = mrow / 49, tokr = mrow - wrel * 49;
        int wg = wbase + wrel;
        int bb = wg >> 6, wrem = wg & 63;
        int r = tokr / 7, c = tokr - r * 7;
        size_t xoff = ((size_t)(bb * NPIX + ((wrem >> 3) * 7 + r) * 56 + (wrem & 7) * 7 + c)) * CDIM;
#pragma unroll
        for (int nf = 0; nf < 12; ++nf) {
            int col = nf * 16 + l15;
            x1[xoff + col] = acc[nf][i] + pbv[nf] + x[xoff + col];
        }
    }
}

// ------------------------------------------------------- k4: depthwise conv3x3 + BN
__global__ void k4_conv(const float* __restrict__ x1, const float* __restrict__ cw,
                        const float* __restrict__ bg, const float* __restrict__ bb,
                        const float* __restrict__ bm, const float* __restrict__ bv,
                        float* __restrict__ x2)
{
    int idx = blockIdx.x * 256 + threadIdx.x;     // ((b*3136+l)*48 + cq)
    int cq  = idx % 48;
    int rem = idx / 48;
    int xx  = rem % 56; rem /= 56;
    int yy  = rem % 56;
    int b   = rem / 56;
    int c0  = cq * 4;
    const float* xb = x1 + (size_t)b * NPIX * CDIM;
    float4 acc = {0, 0, 0, 0};
#pragma unroll
    for (int dy = -1; dy <= 1; ++dy) {
        int y2 = yy + dy;
        if ((unsigned)y2 >= 56u) continue;
#pragma unroll
        for (int dx = -1; dx <= 1; ++dx) {
            int x2c = xx + dx;
            if ((unsigned)x2c >= 56u) continue;
            float4 v = *(const float4*)&xb[(size_t)(y2 * 56 + x2c) * CDIM + c0];
            int tap = (dy + 1) * 3 + (dx + 1);
            acc.x += v.x * cw[(c0 + 0) * 9 + tap];
            acc.y += v.y * cw[(c0 + 1) * 9 + tap];
            acc.z += v.z * cw[(c0 + 2) * 9 + tap];
            acc.w += v.w * cw[(c0 + 3) * 9 + tap];
        }
    }
    float4 o;
    o.x = (acc.x - bm[c0 + 0]) * (bg[c0 + 0] / sqrtf(bv[c0 + 0] + BN_EPS)) + bb[c0 + 0];
    o.y = (acc.y - bm[c0 + 1]) * (bg[c0 + 1] / sqrtf(bv[c0 + 1] + BN_EPS)) + bb[c0 + 1];
    o.z = (acc.z - bm[c0 + 2]) * (bg[c0 + 2] / sqrtf(bv[c0 + 2] + BN_EPS)) + bb[c0 + 2];
    o.w = (acc.w - bm[c0 + 3]) * (bg[c0 + 3] / sqrtf(bv[c0 + 3] + BN_EPS)) + bb[c0 + 3];
    *(float4*)&x2[(size_t)idx * 4] = o;
}

// --------------------- k5: LN2 + FC1 + GELU + FC2 + residual (MFMA, fused per 64 rows)
__global__ __launch_bounds__(256) void k5_mlp_mfma(
    const float* __restrict__ x2, const float* __restrict__ mv2,
    const float* __restrict__ g2, const float* __restrict__ b2,
    const unsigned short* __restrict__ w1sw, const float* __restrict__ fb1,
    const unsigned short* __restrict__ w2sw, const float* __restrict__ fb2,
    float* __restrict__ out)
{
    __shared__ unsigned short hsw[16 * 512];   // hidden chunk 64x128, A-frag layout
    const int tid = threadIdx.x;
    const int w = tid >> 6, L = tid & 63, quad = L >> 4, l15 = L & 15;
    const int m0 = blockIdx.x * 64;
    // ---- A fragments: LN2(x2), 4 m-frags x 6 k-subtiles, kept resident
    float meanv[4], rstdv[4];
    const float* xrp[4];
#pragma unroll
    for (int mf = 0; mf < 4; ++mf) {
        int row = m0 + mf * 16 + l15;
        xrp[mf] = x2 + (size_t)row * CDIM;
        meanv[mf] = mv2[row];
        rstdv[mf] = mv2[NTOKALL + row];
    }
    bf16x8 a[6][4];
#pragma unroll
    for (int kk = 0; kk < 6; ++kk) {
        int c0 = kk * 32 + quad * 8;
        float4 gv0 = *(const float4*)&g2[c0], gv1 = *(const float4*)&g2[c0 + 4];
        float4 bv0 = *(const float4*)&b2[c0], bv1 = *(const float4*)&b2[c0 + 4];
#pragma unroll
        for (int mf = 0; mf < 4; ++mf) {
            float4 xv0 = *(const float4*)&xrp[mf][c0], xv1 = *(const float4*)&xrp[mf][c0 + 4];
            float mm = meanv[mf], rs = rstdv[mf];
            bf16x8 av;
            av[0] = (short)f2bf((xv0.x - mm) * rs * gv0.x + bv0.x);
            av[1] = (short)f2bf((xv0.y - mm) * rs * gv0.y + bv0.y);
            av[2] = (short)f2bf((xv0.z - mm) * rs * gv0.z + bv0.z);
            av[3] = (short)f2bf((xv0.w - mm) * rs * gv0.w + bv0.w);
            av[4] = (short)f2bf((xv1.x - mm) * rs * gv1.x + bv1.x);
            av[5] = (short)f2bf((xv1.y - mm) * rs * gv1.y + bv1.y);
            av[6] = (short)f2bf((xv1.z - mm) * rs * gv1.z + bv1.z);
            av[7] = (short)f2bf((xv1.w - mm) * rs * gv1.w + bv1.w);
            a[kk][mf] = av;
        }
    }
    f32x4 acc2[12];
#pragma unroll
    for (int nf = 0; nf < 12; ++nf) acc2[nf] = (f32x4){0.f, 0.f, 0.f, 0.f};
    const bf16x8* B1 = (const bf16x8*)w1sw;
    const bf16x8* B2 = (const bf16x8*)w2sw;

    for (int ch = 0; ch < 6; ++ch) {
        // ---- FC1: hidden chunk cols [ch*128 + 32w, +32)
        f32x4 acc1[4][2];
#pragma unroll
        for (int mf = 0; mf < 4; ++mf)
#pragma unroll
            for (int nf = 0; nf < 2; ++nf) acc1[mf][nf] = (f32x4){0.f, 0.f, 0.f, 0.f};
#pragma unroll
        for (int kk = 0; kk < 6; ++kk) {
#pragma unroll
            for (int nf = 0; nf < 2; ++nf) {
                bf16x8 bfr = B1[(size_t)((ch * 8 + 2 * w + nf) * 6 + kk) * 64 + L];
#pragma unroll
                for (int mf = 0; mf < 4; ++mf)
                    acc1[mf][nf] = __builtin_amdgcn_mfma_f32_16x16x32_bf16(
                        a[kk][mf], bfr, acc1[mf][nf], 0, 0, 0);
            }
        }
        __syncthreads();   // prior FC2 reads of hsw complete
        // ---- GELU + store hidden in A-frag layout (k-subtile = w)
#pragma unroll
        for (int mf = 0; mf < 4; ++mf) {
#pragma unroll
            for (int nf = 0; nf < 2; ++nf) {
                float bias = fb1[ch * 128 + 32 * w + nf * 16 + l15];
                int hi16 = (((nf * 16 + l15) >> 3) & 3) << 4;
#pragma unroll
                for (int i = 0; i < 4; ++i) {
                    float h = acc1[mf][nf][i] + bias;
                    h = h * 0.5f * (1.0f + erff(h * 0.70710678118654752f));
                    int Ls = (quad * 4 + i) | hi16;
                    hsw[(w * 4 + mf) * 512 + Ls * 8 + (L & 7)] = f2bf(h);
                }
            }
        }
        __syncthreads();
        // ---- FC2 partial: acc2 += Hc(64x128) @ w2[ch*128:+128, :]
#pragma unroll
        for (int kk2 = 0; kk2 < 4; ++kk2) {
            bf16x8 a2 = *(const bf16x8*)&hsw[(kk2 * 4 + w) * 512 + L * 8];
#pragma unroll
            for (int nf2 = 0; nf2 < 12; ++nf2) {
                bf16x8 bfr = B2[(size_t)(nf2 * 24 + ch * 4 + kk2) * 64 + L];
                acc2[nf2] = __builtin_amdgcn_mfma_f32_16x16x32_bf16(a2, bfr, acc2[nf2], 0, 0, 0);
            }
        }
    }
    // ---- epilogue: + fc2_b + residual(x2)
    float fb2v[12];
#pragma unroll
    for (int nf = 0; nf < 12; ++nf) fb2v[nf] = fb2[nf * 16 + l15];
#pragma unroll
    for (int i = 0; i < 4; ++i) {
        int row = m0 + w * 16 + quad * 4 + i;
        const float* xr = x2 + (size_t)row * CDIM;
        float* orow = out + (size_t)row * CDIM;
#pragma unroll
        for (int nf2 = 0; nf2 < 12; ++nf2) {
            int col = nf2 * 16 + l15;
            orow[col] = acc2[nf2][i] + fb2v[nf2] + xr[col];
        }
    }
}

// ------------------------------------------------------------------- launcher
extern "C" void kernel_launch(void* const* d_in, const int* in_sizes, int n_in,
                              void* d_out, int out_size, void* d_ws, size_t ws_size,
                              hipStream_t stream) {
    const float* x     = (const float*)d_in[0];
    const float* g1    = (const float*)d_in[1];
    const float* b1    = (const float*)d_in[2];
    const float* qkvw  = (const float*)d_in[3];
    const float* qkvb  = (const float*)d_in[4];
    const float* abias = (const float*)d_in[5];
    const float* projw = (const float*)d_in[6];
    const float* projb = (const float*)d_in[7];
    const float* convw = (const float*)d_in[8];
    const float* bng   = (const float*)d_in[9];
    const float* bnb   = (const float*)d_in[10];
    const float* bnm   = (const float*)d_in[11];
    const float* bnv   = (const float*)d_in[12];
    const float* g2    = (const float*)d_in[13];
    const float* b2    = (const float*)d_in[14];
    const float* fc1w  = (const float*)d_in[15];
    const float* fc1b  = (const float*)d_in[16];
    const float* fc2w  = (const float*)d_in[17];
    const float* fc2b  = (const float*)d_in[18];
    float* out = (float*)d_out;

    // ws layout (floats):
    //   [0, 19267584)            qkv chunk scratch (14.45M used) / later x2 (19.27M)
    //   [19267584, 19468288)     LN mean/rstd (LN1, then reused for LN2)
    //   [19468288, ...)          swizzled bf16 weights (884,736 B)
    // total = 78,757,888 B
    float* wsf   = (float*)d_ws;
    float* qkvws = wsf;
    float* x2b   = wsf;
    float* mv    = wsf + 19267584;
    unsigned short* qkvw_sw = (unsigned short*)(wsf + 19468288);
    unsigned short* projw_sw = qkvw_sw + 110592;
    unsigned short* fc1_sw   = projw_sw + 36864;
    unsigned short* fc2_sw   = fc1_sw + 147456;

    // weight pre-swizzle (tiny, once per launch)
    kw_swz<<<(216 * 64 + 255) / 256, 256, 0, stream>>>(qkvw, qkvw_sw, CDIM, QKVN);
    kw_swz<<<(72  * 64 + 255) / 256, 256, 0, stream>>>(projw, projw_sw, CDIM, CDIM);
    kw_swz<<<(288 * 64 + 255) / 256, 256, 0, stream>>>(fc1w, fc1_sw, CDIM, HIDDEN);
    kw_swz<<<(288 * 64 + 255) / 256, 256, 0, stream>>>(fc2w, fc2_sw, HIDDEN, CDIM);

    k0_stats<<<NTOKALL / 4, 256, 0, stream>>>(x, mv);
    for (int chunk = 0; chunk < NCHUNK; ++chunk) {
        int wbase = chunk * CHUNKW;
        k1_qkv_mfma<<<dim3(CHUNKM / 64, 3), 256, 0, stream>>>(
            x, mv, g1, b1, qkvw_sw, qkvb, qkvws, wbase);
        k2_attn<<<CHUNKW * 3, 128, 0, stream>>>(qkvws, abias);
        k3_proj_mfma<<<CHUNKM / 64, 256, 0, stream>>>(
            qkvws, x, projw_sw, projb, out, wbase);
    }
    k4_conv<<<(NB * NPIX * 48) / 256, 256, 0, stream>>>(out, convw, bng, bnb, bnm, bnv, x2b);
    k0_stats<<<NTOKALL / 4, 256, 0, stream>>>(x2b, mv);   // LN2 stats
    k5_mlp_mfma<<<NTOKALL / 64, 256, 0, stream>>>(
        x2b, mv, g2, b2, fc1_sw, fc1b, fc2_sw, fc2b, out);
}

// Round 4
// 1068.641 us; speedup vs baseline: 2.0785x; 1.1941x over previous
//
#include <hip/hip_runtime.h>

// Problem constants
#define CDIM   192
#define NHEADS 6
#define KDIM   32
#define NTOK   49          // tokens per window (7x7)
#define NPIX   3136        // 56*56
#define NB     32
#define NWIN   2048        // 32 * 8 * 8
#define CHUNKW 512         // windows per chunk
#define NCHUNK 4
#define CHUNKM (CHUNKW*NTOK)   // 25088
#define QKVN   576
#define HIDDEN 768
#define LN_EPS 1e-5f
#define BN_EPS 1e-5f
#define WSTR   28224       // 3*6*49*32 bf16 elements per window in qkv scratch
#define NTOKALL 100352     // 32*3136

typedef __attribute__((ext_vector_type(8))) short bf16x8;   // 8 bf16 = 4 VGPRs
typedef __attribute__((ext_vector_type(4))) float f32x4;

__device__ __forceinline__ unsigned short f2bf(float f) {
    unsigned u = __float_as_uint(f);
    return (unsigned short)((u + 0x7FFFu + ((u >> 16) & 1u)) >> 16);   // RNE
}
__device__ __forceinline__ float bf2f(unsigned short s) {
    return __uint_as_float(((unsigned)s) << 16);
}

// ------------------------------------------- weight swizzle: fp32 KxN -> bf16 frags
// frag layout: subtile id = (n0/16)*(K/32) + (k0/32); lane L holds
// W[k0 + (L>>4)*8 + j][n0 + (L&15)], j=0..7, stored as 16B per lane.
__global__ void kw_swz(const float* __restrict__ W, unsigned short* __restrict__ o,
                       int K, int N) {
    int t = blockIdx.x * 256 + threadIdx.x;
    int lane = t & 63, sub = t >> 6;
    int ksub = K >> 5;
    int total = (N >> 4) * ksub;
    if (sub >= total) return;
    int nfr = sub / ksub, kk = sub - nfr * ksub;
    int n = nfr * 16 + (lane & 15);
    int kb = kk * 32 + (lane >> 4) * 8;
    unsigned p0 = (unsigned)f2bf(W[(size_t)(kb + 0) * N + n]) |
                  ((unsigned)f2bf(W[(size_t)(kb + 1) * N + n]) << 16);
    unsigned p1 = (unsigned)f2bf(W[(size_t)(kb + 2) * N + n]) |
                  ((unsigned)f2bf(W[(size_t)(kb + 3) * N + n]) << 16);
    unsigned p2 = (unsigned)f2bf(W[(size_t)(kb + 4) * N + n]) |
                  ((unsigned)f2bf(W[(size_t)(kb + 5) * N + n]) << 16);
    unsigned p3 = (unsigned)f2bf(W[(size_t)(kb + 6) * N + n]) |
                  ((unsigned)f2bf(W[(size_t)(kb + 7) * N + n]) << 16);
    uint4 v = {p0, p1, p2, p3};
    *(uint4*)(o + (size_t)(sub * 64 + lane) * 8) = v;
}

// ---------------------------------------------------------------- k0: LN1 stats
__global__ void k0_stats(const float* __restrict__ x, float* __restrict__ mv) {
    int t    = blockIdx.x * 4 + (threadIdx.x >> 6);
    int lane = threadIdx.x & 63;
    const float* row = x + (size_t)t * CDIM;
    float e0 = row[lane], e1 = row[lane + 64], e2 = row[lane + 128];
    float s = e0 + e1 + e2;
    for (int o = 32; o; o >>= 1) s += __shfl_xor(s, o);
    float m = s * (1.0f / 192.0f);
    float d0 = e0 - m, d1 = e1 - m, d2 = e2 - m;
    float v = d0*d0 + d1*d1 + d2*d2;
    for (int o = 32; o; o >>= 1) v += __shfl_xor(v, o);
    if (lane == 0) {
        mv[t] = m;
        mv[NTOKALL + t] = 1.0f / sqrtf(v * (1.0f / 192.0f) + LN_EPS);
    }
}

// ------------------------------------------------- k1: LN1 + QKV GEMM (MFMA bf16)
__global__ __launch_bounds__(256) void k1_qkv_mfma(
    const float* __restrict__ x,  const float* __restrict__ mv,
    const float* __restrict__ g1, const float* __restrict__ b1,
    const unsigned short* __restrict__ wsw, const float* __restrict__ qb,
    unsigned short* __restrict__ qkv, int wbase)
{
    const int tid = threadIdx.x;
    const int w = tid >> 6, L = tid & 63, quad = L >> 4, l15 = L & 15;
    const int m0 = blockIdx.x * 64;
    const int Nt = blockIdx.y;                 // 0..2
    int mA = m0 + w * 16 + l15;
    int gt = wbase * NTOK + mA;
    int wg = gt / 49, tok = gt - wg * 49;
    int bb = wg >> 6, wrem = wg & 63;
    int rr = tok / 7, cc = tok - rr * 7;
    int xrow = bb * NPIX + ((wrem >> 3) * 7 + rr) * 56 + (wrem & 7) * 7 + cc;
    float mean = mv[xrow], rstd = mv[NTOKALL + xrow];
    const float* xr = x + (size_t)xrow * CDIM;
    bf16x8 a[6];
#pragma unroll
    for (int kk = 0; kk < 6; ++kk) {
        int c0 = kk * 32 + quad * 8;
        float4 xv0 = *(const float4*)&xr[c0], xv1 = *(const float4*)&xr[c0 + 4];
        float4 gv0 = *(const float4*)&g1[c0], gv1 = *(const float4*)&g1[c0 + 4];
        float4 bv0 = *(const float4*)&b1[c0], bv1 = *(const float4*)&b1[c0 + 4];
        bf16x8 av;
        av[0] = (short)f2bf((xv0.x - mean) * rstd * gv0.x + bv0.x);
        av[1] = (short)f2bf((xv0.y - mean) * rstd * gv0.y + bv0.y);
        av[2] = (short)f2bf((xv0.z - mean) * rstd * gv0.z + bv0.z);
        av[3] = (short)f2bf((xv0.w - mean) * rstd * gv0.w + bv0.w);
        av[4] = (short)f2bf((xv1.x - mean) * rstd * gv1.x + bv1.x);
        av[5] = (short)f2bf((xv1.y - mean) * rstd * gv1.y + bv1.y);
        av[6] = (short)f2bf((xv1.z - mean) * rstd * gv1.z + bv1.z);
        av[7] = (short)f2bf((xv1.w - mean) * rstd * gv1.w + bv1.w);
        a[kk] = av;
    }
    f32x4 acc[12];
#pragma unroll
    for (int nf = 0; nf < 12; ++nf) acc[nf] = (f32x4){0.f, 0.f, 0.f, 0.f};
    const bf16x8* B = (const bf16x8*)wsw;
#pragma unroll
    for (int kk = 0; kk < 6; ++kk) {
#pragma unroll
        for (int nf = 0; nf < 12; ++nf) {
            bf16x8 bfr = B[(size_t)((Nt * 12 + nf) * 6 + kk) * 64 + L];
            acc[nf] = __builtin_amdgcn_mfma_f32_16x16x32_bf16(a[kk], bfr, acc[nf], 0, 0, 0);
        }
    }
    float qbv[12];
#pragma unroll
    for (int nf = 0; nf < 12; ++nf) qbv[nf] = qb[Nt * 192 + nf * 16 + l15];
#pragma unroll
    for (int i = 0; i < 4; ++i) {
        int mrow = m0 + w * 16 + quad * 4 + i;
        int wrel = mrow / 49, tokr = mrow - wrel * 49;
        unsigned short* obase = qkv + (size_t)wrel * WSTR + tokr * 32;
#pragma unroll
        for (int nf = 0; nf < 12; ++nf) {
            int n = Nt * 192 + nf * 16 + l15;
            int h = n / 96, rem = n - h * 96;
            int part = rem >> 5, d = rem & 31;
            obase[(size_t)(part * 6 + h) * 1568 + d] = f2bf(acc[nf][i] + qbv[nf]);
        }
    }
}

// ----------------------------------------------- k2: windowed attention (head pair)
__global__ __launch_bounds__(128) void k2_attn(
    unsigned short* __restrict__ qkv, const float* __restrict__ abias)
{
    __shared__ float kv[6272];   // [kv part(2)][h(2)][tok 49][d 32], f32
    const int wrel = blockIdx.x / 3;
    const int pair = blockIdx.x - wrel * 3;
    const int h0 = pair * 2;
    unsigned short* base = qkv + (size_t)wrel * WSTR;
    for (int idx = threadIdx.x; idx < 784; idx += 128) {   // 8 elems each
        int part = idx / 392;
        int rem  = idx - part * 392;
        int h    = rem / 196;
        int off8 = rem - h * 196;
        bf16x8 v = *(const bf16x8*)&base[(size_t)((part + 1) * 6 + h0 + h) * 1568 + off8 * 8];
        float* dst = &kv[((part * 2 + h) * 196 + off8) * 8];
        float4 f0 = {bf2f((unsigned short)v[0]), bf2f((unsigned short)v[1]),
                     bf2f((unsigned short)v[2]), bf2f((unsigned short)v[3])};
        float4 f1 = {bf2f((unsigned short)v[4]), bf2f((unsigned short)v[5]),
                     bf2f((unsigned short)v[6]), bf2f((unsigned short)v[7])};
        *(float4*)&dst[0] = f0;
        *(float4*)&dst[4] = f1;
    }
    __syncthreads();
    const int item = threadIdx.x;
    if (item >= 98) return;
    const int h = item / 49;
    const int row = item - h * 49;
    const int hg = h0 + h;
    unsigned short* qptr = base + (size_t)hg * 1568 + row * 32;
    float4 q4[8];
#pragma unroll
    for (int dq2 = 0; dq2 < 4; ++dq2) {
        bf16x8 v = *(const bf16x8*)&qptr[dq2 * 8];
        q4[dq2 * 2]     = (float4){bf2f((unsigned short)v[0]), bf2f((unsigned short)v[1]),
                                   bf2f((unsigned short)v[2]), bf2f((unsigned short)v[3])};
        q4[dq2 * 2 + 1] = (float4){bf2f((unsigned short)v[4]), bf2f((unsigned short)v[5]),
                                   bf2f((unsigned short)v[6]), bf2f((unsigned short)v[7])};
    }
    const int rr = row / 7, rc = row - rr * 7;
    const float scale = 0.17677669529663687f;   // 32^-0.5
    const float* kbase = &kv[(h * 49) * 32];
    const float* vbase = &kv[(98 + h * 49) * 32];
    float s[49];
    for (int j = 0; j < 49; ++j) {
        const float* kr = kbase + j * 32;
        float4 a = {0, 0, 0, 0};
#pragma unroll
        for (int dq = 0; dq < 8; ++dq) {
            float4 k4 = *(const float4*)&kr[dq * 4];
            a.x += q4[dq].x * k4.x; a.y += q4[dq].y * k4.y;
            a.z += q4[dq].z * k4.z; a.w += q4[dq].w * k4.w;
        }
        int jr = j / 7, jc = j - jr * 7;
        int dy = rr > jr ? rr - jr : jr - rr;
        int dx = rc > jc ? rc - jc : jc - rc;
        s[j] = (a.x + a.y + a.z + a.w) * scale + abias[hg * 49 + dy * 7 + dx];
    }
    float mx = s[0];
    for (int j = 1; j < 49; ++j) mx = fmaxf(mx, s[j]);
    float sum = 0.0f;
    for (int j = 0; j < 49; ++j) { s[j] = expf(s[j] - mx); sum += s[j]; }
    float rinv = 1.0f / sum;
    float4 o[8] = {};
    for (int j = 0; j < 49; ++j) {
        float p = s[j];
        const float* vr = vbase + j * 32;
#pragma unroll
        for (int dq = 0; dq < 8; ++dq) {
            float4 v4 = *(const float4*)&vr[dq * 4];
            o[dq].x += p * v4.x; o[dq].y += p * v4.y;
            o[dq].z += p * v4.z; o[dq].w += p * v4.w;
        }
    }
#pragma unroll
    for (int dq = 0; dq < 8; ++dq) {
        uint2 pk;
        pk.x = (unsigned)f2bf(o[dq].x * rinv) | ((unsigned)f2bf(o[dq].y * rinv) << 16);
        pk.y = (unsigned)f2bf(o[dq].z * rinv) | ((unsigned)f2bf(o[dq].w * rinv) << 16);
        *(uint2*)&qptr[dq * 4] = pk;       // overwrite q slot (own row only)
    }
}

// --------------------------- k3: proj GEMM (MFMA) + bias + residual + window reverse
__global__ __launch_bounds__(256) void k3_proj_mfma(
    const unsigned short* __restrict__ qkv, const float* __restrict__ x,
    const unsigned short* __restrict__ wsw, const float* __restrict__ pb,
    float* __restrict__ x1, int wbase)
{
    const int tid = threadIdx.x;
    const int w = tid >> 6, L = tid & 63, quad = L >> 4, l15 = L & 15;
    const int m0 = blockIdx.x * 64;
    const int Nt = blockIdx.y;                 // 0..2, 64 cols each
    int mA = m0 + w * 16 + l15;
    int wrelA = mA / 49, tokA = mA - wrelA * 49;
    const unsigned short* ar = qkv + (size_t)wrelA * WSTR + tokA * 32 + quad * 8;
    bf16x8 a[6];
#pragma unroll
    for (int kk = 0; kk < 6; ++kk)             // head = kk
        a[kk] = *(const bf16x8*)&ar[(size_t)kk * 1568];
    f32x4 acc[4];
#pragma unroll
    for (int nf = 0; nf < 4; ++nf) acc[nf] = (f32x4){0.f, 0.f, 0.f, 0.f};
    const bf16x8* B = (const bf16x8*)wsw;
#pragma unroll
    for (int kk = 0; kk < 6; ++kk) {
#pragma unroll
        for (int nf = 0; nf < 4; ++nf) {
            bf16x8 bfr = B[(size_t)((Nt * 4 + nf) * 6 + kk) * 64 + L];
            acc[nf] = __builtin_amdgcn_mfma_f32_16x16x32_bf16(a[kk], bfr, acc[nf], 0, 0, 0);
        }
    }
    float pbv[4];
#pragma unroll
    for (int nf = 0; nf < 4; ++nf) pbv[nf] = pb[Nt * 64 + nf * 16 + l15];
#pragma unroll
    for (int i = 0; i < 4; ++i) {
        int mrow = m0 + w * 16 + quad * 4 + i;
        int wrel = mrow / 49, tokr = mrow - wrel * 49;
        int wg = wbase + wrel;
        int bb = wg >> 6, wrem = wg & 63;
        int r = tokr / 7, c = tokr - r * 7;
        size_t xoff = ((size_t)(bb * NPIX + ((wrem >> 3) * 7 + r) * 56 + (wrem & 7) * 7 + c)) * CDIM;
#pragma unroll
        for (int nf = 0; nf < 4; ++nf) {
            int col = Nt * 64 + nf * 16 + l15;
            x1[xoff + col] = acc[nf][i] + pbv[nf] + x[xoff + col];
        }
    }
}

// ---------------------- k4: depthwise conv3x3 + BN + LN2 stats (1 wave per token)
__global__ __launch_bounds__(256) void k4_convln(
    const float* __restrict__ x1, const float* __restrict__ cw,
    const float* __restrict__ bg, const float* __restrict__ bb,
    const float* __restrict__ bm, const float* __restrict__ bv,
    float* __restrict__ x2, float* __restrict__ mv)
{
    const int w = threadIdx.x >> 6, lane = threadIdx.x & 63;
    const int t = blockIdx.x * 4 + w;
    const int b = t / NPIX, l = t - b * NPIX;
    const int yy = l / 56, xx = l - yy * 56;
    const bool act = lane < 48;
    const int c0 = lane * 4;
    float4 o = {0, 0, 0, 0};
    if (act) {
        const float* xb = x1 + (size_t)b * NPIX * CDIM;
        float4 acc = {0, 0, 0, 0};
#pragma unroll
        for (int dy = -1; dy <= 1; ++dy) {
            int y2 = yy + dy;
            if ((unsigned)y2 >= 56u) continue;
#pragma unroll
            for (int dx = -1; dx <= 1; ++dx) {
                int x2c = xx + dx;
                if ((unsigned)x2c >= 56u) continue;
                float4 v = *(const float4*)&xb[(size_t)(y2 * 56 + x2c) * CDIM + c0];
                int tap = (dy + 1) * 3 + (dx + 1);
                acc.x += v.x * cw[(c0 + 0) * 9 + tap];
                acc.y += v.y * cw[(c0 + 1) * 9 + tap];
                acc.z += v.z * cw[(c0 + 2) * 9 + tap];
                acc.w += v.w * cw[(c0 + 3) * 9 + tap];
            }
        }
        o.x = (acc.x - bm[c0 + 0]) * (bg[c0 + 0] / sqrtf(bv[c0 + 0] + BN_EPS)) + bb[c0 + 0];
        o.y = (acc.y - bm[c0 + 1]) * (bg[c0 + 1] / sqrtf(bv[c0 + 1] + BN_EPS)) + bb[c0 + 1];
        o.z = (acc.z - bm[c0 + 2]) * (bg[c0 + 2] / sqrtf(bv[c0 + 2] + BN_EPS)) + bb[c0 + 2];
        o.w = (acc.w - bm[c0 + 3]) * (bg[c0 + 3] / sqrtf(bv[c0 + 3] + BN_EPS)) + bb[c0 + 3];
        *(float4*)&x2[(size_t)t * CDIM + c0] = o;
    }
    // LN2 stats (two-pass, butterfly gives sum to all lanes)
    float s = o.x + o.y + o.z + o.w;
    for (int off = 32; off; off >>= 1) s += __shfl_xor(s, off);
    float m = s * (1.0f / 192.0f);
    float d0 = o.x - m, d1 = o.y - m, d2 = o.z - m, d3 = o.w - m;
    float v2 = act ? (d0*d0 + d1*d1 + d2*d2 + d3*d3) : 0.0f;
    for (int off = 32; off; off >>= 1) v2 += __shfl_xor(v2, off);
    if (lane == 0) {
        mv[t] = m;
        mv[NTOKALL + t] = 1.0f / sqrtf(v2 * (1.0f / 192.0f) + LN_EPS);
    }
}

// --------------- k5: LN2 + FC1 + GELU + FC2 + residual (MFMA, LDS-staged A-frags)
__global__ __launch_bounds__(256) void k5_mlp_mfma(
    const float* __restrict__ x2, const float* __restrict__ mv2,
    const float* __restrict__ g2, const float* __restrict__ b2,
    const unsigned short* __restrict__ w1sw, const float* __restrict__ fb1,
    const unsigned short* __restrict__ w2sw, const float* __restrict__ fb2,
    float* __restrict__ out)
{
    __shared__ unsigned short aFrag[24 * 512];   // [mf 4][kk 6][lane 64][8 bf16] = 24KB
    __shared__ unsigned short hsw[16 * 512];     // hidden chunk 64x128, A-frag layout
    const int tid = threadIdx.x;
    const int w = tid >> 6, L = tid & 63, quad = L >> 4, l15 = L & 15;
    const int m0 = blockIdx.x * 64;
    // ---- build LN2(x2) A-fragments into LDS (cooperative, 6 slots/thread)
#pragma unroll
    for (int rsl = 0; rsl < 6; ++rsl) {
        int s = tid + 256 * rsl;                 // 0..1535
        int mf = s / 384, rem = s - mf * 384;
        int kk = rem >> 6, La = rem & 63;
        int row = m0 + mf * 16 + (La & 15);
        int c0 = kk * 32 + (La >> 4) * 8;
        float mm = mv2[row], rs = mv2[NTOKALL + row];
        const float* xr = x2 + (size_t)row * CDIM + c0;
        float4 xv0 = *(const float4*)&xr[0], xv1 = *(const float4*)&xr[4];
        float4 gv0 = *(const float4*)&g2[c0], gv1 = *(const float4*)&g2[c0 + 4];
        float4 bv0 = *(const float4*)&b2[c0], bv1 = *(const float4*)&b2[c0 + 4];
        bf16x8 av;
        av[0] = (short)f2bf((xv0.x - mm) * rs * gv0.x + bv0.x);
        av[1] = (short)f2bf((xv0.y - mm) * rs * gv0.y + bv0.y);
        av[2] = (short)f2bf((xv0.z - mm) * rs * gv0.z + bv0.z);
        av[3] = (short)f2bf((xv0.w - mm) * rs * gv0.w + bv0.w);
        av[4] = (short)f2bf((xv1.x - mm) * rs * gv1.x + bv1.x);
        av[5] = (short)f2bf((xv1.y - mm) * rs * gv1.y + bv1.y);
        av[6] = (short)f2bf((xv1.z - mm) * rs * gv1.z + bv1.z);
        av[7] = (short)f2bf((xv1.w - mm) * rs * gv1.w + bv1.w);
        *(bf16x8*)&aFrag[(size_t)s * 8] = av;
    }
    __syncthreads();

    f32x4 acc2[12];
#pragma unroll
    for (int nf = 0; nf < 12; ++nf) acc2[nf] = (f32x4){0.f, 0.f, 0.f, 0.f};
    const bf16x8* B1 = (const bf16x8*)w1sw;
    const bf16x8* B2 = (const bf16x8*)w2sw;

    for (int ch = 0; ch < 6; ++ch) {
        // ---- FC1: hidden cols [ch*128 + 32w, +32) for all 64 rows
        f32x4 acc1[4][2];
#pragma unroll
        for (int mf = 0; mf < 4; ++mf)
#pragma unroll
            for (int nf = 0; nf < 2; ++nf) acc1[mf][nf] = (f32x4){0.f, 0.f, 0.f, 0.f};
#pragma unroll
        for (int kk = 0; kk < 6; ++kk) {
            bf16x8 bfr0 = B1[(size_t)((ch * 8 + 2 * w + 0) * 6 + kk) * 64 + L];
            bf16x8 bfr1 = B1[(size_t)((ch * 8 + 2 * w + 1) * 6 + kk) * 64 + L];
#pragma unroll
            for (int mf = 0; mf < 4; ++mf) {
                bf16x8 av = *(const bf16x8*)&aFrag[(size_t)((mf * 6 + kk) * 64 + L) * 8];
                acc1[mf][0] = __builtin_amdgcn_mfma_f32_16x16x32_bf16(av, bfr0, acc1[mf][0], 0, 0, 0);
                acc1[mf][1] = __builtin_amdgcn_mfma_f32_16x16x32_bf16(av, bfr1, acc1[mf][1], 0, 0, 0);
            }
        }
        __syncthreads();   // prior FC2 reads of hsw complete
        // ---- GELU + store hidden in A-frag layout (k-subtile = w)
#pragma unroll
        for (int mf = 0; mf < 4; ++mf) {
#pragma unroll
            for (int nf = 0; nf < 2; ++nf) {
                float bias = fb1[ch * 128 + 32 * w + nf * 16 + l15];
                int hi16 = (((nf * 16 + l15) >> 3) & 3) << 4;
#pragma unroll
                for (int i = 0; i < 4; ++i) {
                    float h = acc1[mf][nf][i] + bias;
                    h = h * 0.5f * (1.0f + erff(h * 0.70710678118654752f));
                    int Ls = (quad * 4 + i) | hi16;
                    hsw[(w * 4 + mf) * 512 + Ls * 8 + (L & 7)] = f2bf(h);
                }
            }
        }
        __syncthreads();
        // ---- FC2 partial: acc2 += Hc(64x128) @ w2[ch*128:+128, :]
#pragma unroll
        for (int kk2 = 0; kk2 < 4; ++kk2) {
            bf16x8 a2 = *(const bf16x8*)&hsw[(kk2 * 4 + w) * 512 + L * 8];
#pragma unroll
            for (int nf2 = 0; nf2 < 12; ++nf2) {
                bf16x8 bfr = B2[(size_t)(nf2 * 24 + ch * 4 + kk2) * 64 + L];
                acc2[nf2] = __builtin_amdgcn_mfma_f32_16x16x32_bf16(a2, bfr, acc2[nf2], 0, 0, 0);
            }
        }
    }
    // ---- epilogue: + fc2_b + residual(x2)
#pragma unroll
    for (int i = 0; i < 4; ++i) {
        int row = m0 + w * 16 + quad * 4 + i;
        const float* xr = x2 + (size_t)row * CDIM;
        float* orow = out + (size_t)row * CDIM;
#pragma unroll
        for (int nf2 = 0; nf2 < 12; ++nf2) {
            int col = nf2 * 16 + l15;
            orow[col] = acc2[nf2][i] + fb2[col] + xr[col];
        }
    }
}

// ------------------------------------------------------------------- launcher
extern "C" void kernel_launch(void* const* d_in, const int* in_sizes, int n_in,
                              void* d_out, int out_size, void* d_ws, size_t ws_size,
                              hipStream_t stream) {
    const float* x     = (const float*)d_in[0];
    const float* g1    = (const float*)d_in[1];
    const float* b1    = (const float*)d_in[2];
    const float* qkvw  = (const float*)d_in[3];
    const float* qkvb  = (const float*)d_in[4];
    const float* abias = (const float*)d_in[5];
    const float* projw = (const float*)d_in[6];
    const float* projb = (const float*)d_in[7];
    const float* convw = (const float*)d_in[8];
    const float* bng   = (const float*)d_in[9];
    const float* bnb   = (const float*)d_in[10];
    const float* bnm   = (const float*)d_in[11];
    const float* bnv   = (const float*)d_in[12];
    const float* g2    = (const float*)d_in[13];
    const float* b2    = (const float*)d_in[14];
    const float* fc1w  = (const float*)d_in[15];
    const float* fc1b  = (const float*)d_in[16];
    const float* fc2w  = (const float*)d_in[17];
    const float* fc2b  = (const float*)d_in[18];
    float* out = (float*)d_out;

    // ws layout (floats):
    //   [0, 19267584)            qkv bf16 chunk scratch (28.9MB used) / later x2 fp32 (77MB)
    //   [19267584, 19468288)     LN mean/rstd (LN1, then overwritten by LN2 stats in k4)
    //   [19468288, ...)          swizzled bf16 weights (884,736 B)
    float* wsf   = (float*)d_ws;
    unsigned short* qkvws = (unsigned short*)wsf;
    float* x2b   = wsf;
    float* mv    = wsf + 19267584;
    unsigned short* qkvw_sw = (unsigned short*)(wsf + 19468288);
    unsigned short* projw_sw = qkvw_sw + 110592;
    unsigned short* fc1_sw   = projw_sw + 36864;
    unsigned short* fc2_sw   = fc1_sw + 147456;

    kw_swz<<<(216 * 64 + 255) / 256, 256, 0, stream>>>(qkvw, qkvw_sw, CDIM, QKVN);
    kw_swz<<<(72  * 64 + 255) / 256, 256, 0, stream>>>(projw, projw_sw, CDIM, CDIM);
    kw_swz<<<(288 * 64 + 255) / 256, 256, 0, stream>>>(fc1w, fc1_sw, CDIM, HIDDEN);
    kw_swz<<<(288 * 64 + 255) / 256, 256, 0, stream>>>(fc2w, fc2_sw, HIDDEN, CDIM);

    k0_stats<<<NTOKALL / 4, 256, 0, stream>>>(x, mv);
    for (int chunk = 0; chunk < NCHUNK; ++chunk) {
        int wbase = chunk * CHUNKW;
        k1_qkv_mfma<<<dim3(CHUNKM / 64, 3), 256, 0, stream>>>(
            x, mv, g1, b1, qkvw_sw, qkvb, qkvws, wbase);
        k2_attn<<<CHUNKW * 3, 128, 0, stream>>>(qkvws, abias);
        k3_proj_mfma<<<dim3(CHUNKM / 64, 3), 256, 0, stream>>>(
            qkvws, x, projw_sw, projb, out, wbase);
    }
    k4_convln<<<NTOKALL / 4, 256, 0, stream>>>(out, convw, bng, bnb, bnm, bnv, x2b, mv);
    k5_mlp_mfma<<<NTOKALL / 64, 256, 0, stream>>>(
        x2b, mv, g2, b2, fc1_sw, fc1b, fc2_sw, fc2b, out);
}